// Round 7
// baseline (22.155 us; speedup 1.0000x reference)
//
#include <hip/hip_runtime.h>

// Median blur 3x3, zero padding, lower median (== true median for 9 elems).
// x: (16, 3, 512, 512) float32 contiguous. Out same shape/dtype.
//
// R7: halo columns via cross-lane shuffle instead of strided scalar loads
// (left = lane-1's v.w, right = lane+1's v.x; only the 2 wave-edge lanes
// do a masked 1-lane load). Persistent 1536-block grid x 2 strips -> all
// blocks resident, zero drain tail. ROWS=4, preload-all, NT stores.

typedef float vf4 __attribute__((ext_vector_type(4)));

__device__ __forceinline__ void s2(float& a, float& b) {
    float t = fminf(a, b);
    b = fmaxf(a, b);
    a = t;
}
__device__ __forceinline__ float max3(float a, float b, float c) {
    return fmaxf(fmaxf(a, b), c);
}
__device__ __forceinline__ float min3(float a, float b, float c) {
    return fminf(fminf(a, b), c);
}
__device__ __forceinline__ float med3(float a, float b, float c) {
    return fmaxf(fminf(a, b), fminf(fmaxf(a, b), c));
}

constexpr int ROWS = 4;           // output rows per thread
constexpr int VBLK = 16 * 3 * (512 / ROWS) * (512 / 4) / 256;  // 3072 virtual blocks
constexpr int GRID = VBLK / 2;    // 1536 real blocks, 2 strips each

__global__ __launch_bounds__(256, 8) void median_blur_kernel(
        const float* __restrict__ x, float* __restrict__ out) {
    constexpr int W = 512, H = 512, W4 = W / 4;   // 128 groups/row
    constexpr int RB = H / ROWS;                  // 128 row-blocks

    int lane = threadIdx.x & 63;

#pragma unroll
    for (int it = 0; it < 2; ++it) {
        int vb = it * GRID + blockIdx.x;
        // Bijective XCD-chunked swizzle over the 3072 virtual blocks.
        int bid = (vb & 7) * (VBLK >> 3) + (vb >> 3);

        int gid = bid * 256 + threadIdx.x;
        int w4 = gid & (W4 - 1);
        int rb = (gid >> 7) & (RB - 1);
        int bc = gid >> 14;

        const float* plane = x + (size_t)bc * H * W;
        float* oplane = out + (size_t)bc * H * W;
        int c0 = w4 * 4;
        int h0 = rb * ROWS;

        // Preload all 6 halo rows; halo columns come from neighbor lanes.
        float r[ROWS + 2][6];
#pragma unroll
        for (int i = 0; i < ROWS + 2; ++i) {
            int rr = h0 - 1 + i;
            if (rr >= 0 && rr < H) {          // wave-uniform branch
                const float* p = plane + rr * W + c0;
                vf4 v = *reinterpret_cast<const vf4*>(p);
                r[i][1] = v.x; r[i][2] = v.y; r[i][3] = v.z; r[i][4] = v.w;
                float left  = __shfl_up(v.w, 1);
                float right = __shfl_down(v.x, 1);
                if (lane == 0)  left  = (c0 > 0)     ? p[-1] : 0.0f;
                if (lane == 63) right = (c0 + 4 < W) ? p[4]  : 0.0f;
                r[i][0] = left; r[i][5] = right;
            } else {
                r[i][0] = r[i][1] = r[i][2] = 0.0f;
                r[i][3] = r[i][4] = r[i][5] = 0.0f;
            }
        }

#pragma unroll
        for (int i = 0; i < ROWS; ++i) {
            // Sort the 6 columns of 3 (lo <= mi <= hi), shared by 4 outputs.
            float lo[6], mi[6], hi[6];
#pragma unroll
            for (int j = 0; j < 6; ++j) {
                float a = r[i][j], b = r[i + 1][j], c = r[i + 2][j];
                s2(b, c); s2(a, c); s2(a, b);
                lo[j] = a; mi[j] = b; hi[j] = c;
            }

            vf4 o;
            o.x = med3(max3(lo[0], lo[1], lo[2]), med3(mi[0], mi[1], mi[2]), min3(hi[0], hi[1], hi[2]));
            o.y = med3(max3(lo[1], lo[2], lo[3]), med3(mi[1], mi[2], mi[3]), min3(hi[1], hi[2], hi[3]));
            o.z = med3(max3(lo[2], lo[3], lo[4]), med3(mi[2], mi[3], mi[4]), min3(hi[2], hi[3], hi[4]));
            o.w = med3(max3(lo[3], lo[4], lo[5]), med3(mi[3], mi[4], mi[5]), min3(hi[3], hi[4], hi[5]));

            float* po = oplane + (size_t)(h0 + i) * W + c0;
            __builtin_nontemporal_store(o, reinterpret_cast<vf4*>(po));
        }
    }
}

extern "C" void kernel_launch(void* const* d_in, const int* in_sizes, int n_in,
                              void* d_out, int out_size, void* d_ws, size_t ws_size,
                              hipStream_t stream) {
    const float* x = (const float*)d_in[0];
    float* out = (float*)d_out;
    median_blur_kernel<<<GRID, 256, 0, stream>>>(x, out);
}

// Round 8
// 22.080 us; speedup vs baseline: 1.0034x; 1.0034x over previous
//
#include <hip/hip_runtime.h>

// Median blur 3x3, zero padding, lower median (== true median for 9 elems).
// x: (16, 3, 512, 512) float32 contiguous. Out same shape/dtype.
//
// R8: exactly R6 (ROWS=4 preload-all, scalar edge loads, 3072 blocks,
// XCD swizzle, launch_bounds(256,8)) but with PLAIN stores instead of
// nontemporal: let the 256 MiB Infinity Cache absorb the 50 MB output
// (write-back) and keep the 50 MB input L3-resident across replays.

typedef float vf4 __attribute__((ext_vector_type(4)));

__device__ __forceinline__ void s2(float& a, float& b) {
    float t = fminf(a, b);
    b = fmaxf(a, b);
    a = t;
}
__device__ __forceinline__ float max3(float a, float b, float c) {
    return fmaxf(fmaxf(a, b), c);
}
__device__ __forceinline__ float min3(float a, float b, float c) {
    return fminf(fminf(a, b), c);
}
__device__ __forceinline__ float med3(float a, float b, float c) {
    return fmaxf(fminf(a, b), fminf(fmaxf(a, b), c));
}

constexpr int ROWS = 4;  // output rows per thread

__global__ __launch_bounds__(256, 8) void median_blur_kernel(
        const float* __restrict__ x, float* __restrict__ out) {
    constexpr int W = 512, H = 512, W4 = W / 4;   // 128 groups/row
    constexpr int RB = H / ROWS;                  // 128 row-blocks

    // Bijective XCD-chunked swizzle (gridDim.x == 3072, divisible by 8):
    // consecutive bids (vertically adjacent strips) share an XCD L2.
    int cpx = gridDim.x >> 3;
    int bid = (blockIdx.x & 7) * cpx + (blockIdx.x >> 3);

    int gid = bid * blockDim.x + threadIdx.x;
    int w4 = gid & (W4 - 1);
    int rb = (gid >> 7) & (RB - 1);
    int bc = gid >> 14;

    const float* plane = x + (size_t)bc * H * W;
    float* oplane = out + (size_t)bc * H * W;
    int c0 = w4 * 4;
    int h0 = rb * ROWS;

    // Preload all ROWS+2 = 6 halo rows; all loads issue before any use.
    float r[ROWS + 2][6];
#pragma unroll
    for (int i = 0; i < ROWS + 2; ++i) {
        int rr = h0 - 1 + i;
        if (rr >= 0 && rr < H) {
            const float* p = plane + rr * W + c0;
            vf4 v = *reinterpret_cast<const vf4*>(p);
            r[i][1] = v.x; r[i][2] = v.y; r[i][3] = v.z; r[i][4] = v.w;
            r[i][0] = (c0 > 0)     ? p[-1] : 0.0f;
            r[i][5] = (c0 + 4 < W) ? p[4]  : 0.0f;
        } else {
            r[i][0] = r[i][1] = r[i][2] = 0.0f;
            r[i][3] = r[i][4] = r[i][5] = 0.0f;
        }
    }

#pragma unroll
    for (int i = 0; i < ROWS; ++i) {
        // Sort the 6 columns of 3 (lo <= mi <= hi), shared across 4 outputs.
        float lo[6], mi[6], hi[6];
#pragma unroll
        for (int j = 0; j < 6; ++j) {
            float a = r[i][j], b = r[i + 1][j], c = r[i + 2][j];
            s2(b, c); s2(a, c); s2(a, b);
            lo[j] = a; mi[j] = b; hi[j] = c;
        }

        vf4 o;
        o.x = med3(max3(lo[0], lo[1], lo[2]), med3(mi[0], mi[1], mi[2]), min3(hi[0], hi[1], hi[2]));
        o.y = med3(max3(lo[1], lo[2], lo[3]), med3(mi[1], mi[2], mi[3]), min3(hi[1], hi[2], hi[3]));
        o.z = med3(max3(lo[2], lo[3], lo[4]), med3(mi[2], mi[3], mi[4]), min3(hi[2], hi[3], hi[4]));
        o.w = med3(max3(lo[3], lo[4], lo[5]), med3(mi[3], mi[4], mi[5]), min3(hi[3], hi[4], hi[5]));

        float* po = oplane + (size_t)(h0 + i) * W + c0;
        *reinterpret_cast<vf4*>(po) = o;
    }
}

extern "C" void kernel_launch(void* const* d_in, const int* in_sizes, int n_in,
                              void* d_out, int out_size, void* d_ws, size_t ws_size,
                              hipStream_t stream) {
    const float* x = (const float*)d_in[0];
    float* out = (float*)d_out;
    // 16*3 planes * 128 row-blocks * 128 groups = 786,432 threads -> 3072 blocks
    constexpr int threads = 256;
    constexpr int total = 16 * 3 * (512 / ROWS) * (512 / 4);
    median_blur_kernel<<<total / threads, threads, 0, stream>>>(x, out);
}